// Round 1
// 268.860 us; speedup vs baseline: 1.0006x; 1.0006x over previous
//
#include <hip/hip_runtime.h>

#define NN 100000
#define NE 1600000
#define KB 782      // coarse buckets: ceil(100000/128)
#define BSH 7       // bucket = dst >> 7; 128 nodes per bucket
#define MAXB 4096   // fixed slots per bucket (mean 2046, max ~2250 — safe)
#define PBLK 200    // cpart blocks; NE/PBLK = 8000 edges per block

// Workspace layout in 4-byte units (total 25,850,368 uints = 103.4 MB):
#define OFF_CC    0            // 1024: per-bucket edge counts
#define OFF_RST   1024         // 100096: per-node edge-range start (global slot index)
#define OFF_RDG   101120       // 100096: per-node degree
#define OFF_STAGE 201216       // KB*MAXB: packed (dstLow<<17)|src, slotted; node-sorted src after sort_kernel
#define OFF_XB    3404288      // x bf16 [100096,128]
#define OFF_XF8   9810432      // x fp8 [100096,128]; pb bf16 [100096,64] aliases (xf8 dead after agg1g)
#define OFF_MEANB 13013504     // mean bf16 [100096,128]; meanp fp32 [100096,64] aliases
#define OFF_HB    19419648     // h bf16 [100096,128]
#define OFF_W1LP  25825792     // packed weights bf16
#define OFF_W1RP  (25825792 + 8192)
#define OFF_W2LP  (25825792 + 16384)
#define OFF_W2RP  (25825792 + 20480)

typedef __bf16 bf16x8 __attribute__((ext_vector_type(8)));
typedef float f32x4 __attribute__((ext_vector_type(4)));
typedef float f32x2 __attribute__((ext_vector_type(2)));

static __device__ __forceinline__ ushort f2bf(float f) {
    unsigned u = __float_as_uint(f);
    return (ushort)((u + 0x7fffu + ((u >> 16) & 1u)) >> 16);
}
static __device__ __forceinline__ float bflo(unsigned u) { return __uint_as_float(u << 16); }
static __device__ __forceinline__ float bfhi(unsigned u) { return __uint_as_float(u & 0xffff0000u); }

// ---------------------------------------------------------------------------
// x (fp32) -> xb (bf16, for gemm1) and xf8 (fp8 e4m3, for agg1 gather).
// ---------------------------------------------------------------------------
__global__ void cvt_kernel(const float* __restrict__ x, ushort* __restrict__ xb,
                           unsigned* __restrict__ xf8) {
    int i = blockIdx.x * 256 + threadIdx.x;  // covers NN*128/4 = 3.2M
    float4 v = ((const float4*)x)[i];
    uint2 o;
    o.x = (unsigned)f2bf(v.x) | ((unsigned)f2bf(v.y) << 16);
    o.y = (unsigned)f2bf(v.z) | ((unsigned)f2bf(v.w) << 16);
    ((uint2*)xb)[i] = o;
    int p8 = __builtin_amdgcn_cvt_pk_fp8_f32(v.x, v.y, 0, false);
    p8 = __builtin_amdgcn_cvt_pk_fp8_f32(v.z, v.w, p8, true);
    xf8[i] = (unsigned)p8;
}

// ---------------------------------------------------------------------------
// Pack all 4 weight matrices fp32 -> bf16 MFMA B-frag layout.
// ---------------------------------------------------------------------------
__global__ void pack_kernel(const float* __restrict__ W1l, const float* __restrict__ W1r,
                            const float* __restrict__ W2l, const float* __restrict__ W2r,
                            ushort* __restrict__ w1lp, ushort* __restrict__ w1rp,
                            ushort* __restrict__ w2lp, ushort* __restrict__ w2rp) {
    int blk = blockIdx.x;
    const float* W;
    ushort* out;
    int N, frag0;
    if (blk < 8)       { W = W1l; out = w1lp; N = 128; frag0 = blk * 4; }
    else if (blk < 16) { W = W1r; out = w1rp; N = 128; frag0 = (blk - 8) * 4; }
    else if (blk < 20) { W = W2l; out = w2lp; N = 64;  frag0 = (blk - 16) * 4; }
    else               { W = W2r; out = w2rp; N = 64;  frag0 = (blk - 20) * 4; }
    int lane = threadIdx.x & 63;
    int frag = frag0 + (threadIdx.x >> 6);
    int NT = N >> 4;
    int ktile = frag / NT, ntile = frag - ktile * NT;
    int k = ktile * 32 + (lane >> 4) * 8;
    int n = ntile * 16 + (lane & 15);
    ushort tmp[8];
#pragma unroll
    for (int j = 0; j < 8; ++j) tmp[j] = f2bf(W[(k + j) * N + n]);
    uint4 o;
    o.x = (unsigned)tmp[0] | ((unsigned)tmp[1] << 16);
    o.y = (unsigned)tmp[2] | ((unsigned)tmp[3] << 16);
    o.z = (unsigned)tmp[4] | ((unsigned)tmp[5] << 16);
    o.w = (unsigned)tmp[6] | ((unsigned)tmp[7] << 16);
    *(uint4*)&out[(frag * 64 + lane) * 8] = o;
}

// ---------------------------------------------------------------------------
// Coarse partition, fixed-capacity slots. Block-level LDS histogram -> one
// global atomicAdd per (block,bucket) -> LDS-cursor placement.
// ---------------------------------------------------------------------------
__global__ __launch_bounds__(1024) void cpart_kernel(const int* __restrict__ src,
                                                     const int* __restrict__ dst,
                                                     int* __restrict__ cc,
                                                     unsigned* __restrict__ stage) {
    __shared__ int hist[KB];
    __shared__ int cur[KB];
    int t = threadIdx.x;
    int e0 = blockIdx.x * (NE / PBLK);
    int e1 = e0 + (NE / PBLK);
    for (int i = t; i < KB; i += 1024) hist[i] = 0;
    __syncthreads();
    for (int e = e0 + t; e < e1; e += 1024)
        atomicAdd(&hist[dst[e] >> BSH], 1);
    __syncthreads();
    for (int i = t; i < KB; i += 1024) {
        int c = hist[i];
        cur[i] = c ? atomicAdd(&cc[i], c) : 0;
    }
    __syncthreads();
    for (int e = e0 + t; e < e1; e += 1024) {
        int d = dst[e];
        int bkt = d >> BSH;
        int p = atomicAdd(&cur[bkt], 1);
        if (p < MAXB)
            stage[bkt * MAXB + p] = ((unsigned)(d & 127) << 17) | (unsigned)src[e];
    }
}

// ---------------------------------------------------------------------------
// Sort: one block per bucket. Build the local CSR in LDS (paid ONCE), write
// the node-sorted src list back into the stage slots in place, and emit
// global rstart/rdeg so the gather kernels need no LDS and no CSR build.
// ---------------------------------------------------------------------------
__global__ __launch_bounds__(256) void sort_kernel(unsigned* __restrict__ stage,
                                                   const int* __restrict__ cc,
                                                   int* __restrict__ rstart,
                                                   int* __restrict__ rdeg) {
    __shared__ unsigned ssrc[MAXB];
    __shared__ int sc[128];
    __shared__ int loff[129];
    __shared__ int lcur[128];
    int t = threadIdx.x;
    int b = blockIdx.x;
    unsigned* st = stage + b * MAXB;
    int cnt = min(cc[b], MAXB);

    if (t < 128) lcur[t] = 0;
    __syncthreads();
    for (int i = t; i < cnt; i += 256) atomicAdd(&lcur[st[i] >> 17], 1);
    __syncthreads();
    if (t < 128) sc[t] = lcur[t];
    __syncthreads();
    for (int off = 1; off < 128; off <<= 1) {
        int v = (t < 128 && t >= off) ? sc[t - off] : 0;
        __syncthreads();
        if (t < 128) sc[t] += v;
        __syncthreads();
    }
    if (t < 128) {
        int excl = (t == 0) ? 0 : sc[t - 1];
        loff[t] = excl;
        lcur[t] = excl;
    }
    if (t == 127) loff[128] = sc[127];
    __syncthreads();
    for (int i = t; i < cnt; i += 256) {
        unsigned v = st[i];
        int p = atomicAdd(&lcur[v >> 17], 1);
        ssrc[p] = v & 0x1FFFFu;
    }
    __syncthreads();
    for (int i = t; i < cnt; i += 256) st[i] = ssrc[i];
    int node0 = b << BSH;
    if (t < 128 && node0 + t < NN) {
        rstart[node0 + t] = b * MAXB + loff[t];
        rdeg[node0 + t] = loff[t + 1] - loff[t];
    }
}

// ---------------------------------------------------------------------------
// Layer-1 gather (fp8, zero LDS): quarter-wave (16 lanes) per node, lane owns
// 8 channels (uint2 = 8 fp8; 16 lanes x 8B = 128B coalesced row).
// 2-NODE INTERLEAVE: each 16-lane group owns TWO nodes and interleaves their
// edge streams -> 8 row-gathers in flight per group (was 4) to cover the
// random-gather latency through L2/L3. Grid 3125 x 256 = 100000 nodes.
// ---------------------------------------------------------------------------
static __device__ __forceinline__ void accum8(float* a, uint2 u) {
    f32x2 p0 = __builtin_amdgcn_cvt_pk_f32_fp8(u.x, false);
    f32x2 p1 = __builtin_amdgcn_cvt_pk_f32_fp8(u.x, true);
    f32x2 p2 = __builtin_amdgcn_cvt_pk_f32_fp8(u.y, false);
    f32x2 p3 = __builtin_amdgcn_cvt_pk_f32_fp8(u.y, true);
    a[0] += p0.x; a[1] += p0.y; a[2] += p1.x; a[3] += p1.y;
    a[4] += p2.x; a[5] += p2.y; a[6] += p3.x; a[7] += p3.y;
}

static __device__ __forceinline__ void writeRow8(ushort* __restrict__ meanb, int node,
                                                 int l4, const float* a, int deg) {
    float inv = 1.0f / fmaxf((float)deg, 1.0f);
    uint4 o;
    o.x = (unsigned)f2bf(a[0] * inv) | ((unsigned)f2bf(a[1] * inv) << 16);
    o.y = (unsigned)f2bf(a[2] * inv) | ((unsigned)f2bf(a[3] * inv) << 16);
    o.z = (unsigned)f2bf(a[4] * inv) | ((unsigned)f2bf(a[5] * inv) << 16);
    o.w = (unsigned)f2bf(a[6] * inv) | ((unsigned)f2bf(a[7] * inv) << 16);
    *(uint4*)&meanb[node * 128 + 8 * l4] = o;
}

__global__ __launch_bounds__(256) void agg1g_kernel(const unsigned* __restrict__ es,
                                                    const int* __restrict__ rstart,
                                                    const int* __restrict__ rdeg,
                                                    const unsigned* __restrict__ xf8,
                                                    ushort* __restrict__ meanb) {
    int t = threadIdx.x;
    int l4 = t & 15;
    int nA = blockIdx.x * 32 + (t >> 4) * 2;
    int nB = nA + 1;
    int sA = rstart[nA], dA = rdeg[nA];
    int sB = rstart[nB], dB = rdeg[nB];
    const uint2* xv = (const uint2*)xf8;  // row = 16 uint2 (128 fp8)
    float aA[8] = {0.f, 0.f, 0.f, 0.f, 0.f, 0.f, 0.f, 0.f};
    float aB[8] = {0.f, 0.f, 0.f, 0.f, 0.f, 0.f, 0.f, 0.f};
    int eA = 0, eB = 0;
    // Interleaved main loop: 8 index loads + 8 row gathers in flight.
    while (eA + 4 <= dA && eB + 4 <= dB) {
        int qa0 = es[sA + eA + 0], qa1 = es[sA + eA + 1];
        int qa2 = es[sA + eA + 2], qa3 = es[sA + eA + 3];
        int qb0 = es[sB + eB + 0], qb1 = es[sB + eB + 1];
        int qb2 = es[sB + eB + 2], qb3 = es[sB + eB + 3];
        uint2 ua0 = xv[qa0 * 16 + l4], ua1 = xv[qa1 * 16 + l4];
        uint2 ua2 = xv[qa2 * 16 + l4], ua3 = xv[qa3 * 16 + l4];
        uint2 ub0 = xv[qb0 * 16 + l4], ub1 = xv[qb1 * 16 + l4];
        uint2 ub2 = xv[qb2 * 16 + l4], ub3 = xv[qb3 * 16 + l4];
        accum8(aA, ua0); accum8(aA, ua1); accum8(aA, ua2); accum8(aA, ua3);
        accum8(aB, ub0); accum8(aB, ub1); accum8(aB, ub2); accum8(aB, ub3);
        eA += 4; eB += 4;
    }
    // Drain stream A.
    for (; eA + 4 <= dA; eA += 4) {
        int q0 = es[sA + eA + 0], q1 = es[sA + eA + 1];
        int q2 = es[sA + eA + 2], q3 = es[sA + eA + 3];
        uint2 u0 = xv[q0 * 16 + l4], u1 = xv[q1 * 16 + l4];
        uint2 u2 = xv[q2 * 16 + l4], u3 = xv[q3 * 16 + l4];
        accum8(aA, u0); accum8(aA, u1); accum8(aA, u2); accum8(aA, u3);
    }
    for (; eA < dA; ++eA) accum8(aA, xv[es[sA + eA] * 16 + l4]);
    // Drain stream B.
    for (; eB + 4 <= dB; eB += 4) {
        int q0 = es[sB + eB + 0], q1 = es[sB + eB + 1];
        int q2 = es[sB + eB + 2], q3 = es[sB + eB + 3];
        uint2 u0 = xv[q0 * 16 + l4], u1 = xv[q1 * 16 + l4];
        uint2 u2 = xv[q2 * 16 + l4], u3 = xv[q3 * 16 + l4];
        accum8(aB, u0); accum8(aB, u1); accum8(aB, u2); accum8(aB, u3);
    }
    for (; eB < dB; ++eB) accum8(aB, xv[es[sB + eB] * 16 + l4]);

    writeRow8(meanb, nA, l4, aA, dA);
    writeRow8(meanb, nB, l4, aB, dB);
}

// ---------------------------------------------------------------------------
// Layer-2 gather (bf16 pb, zero LDS): half-wave (32 lanes) per node, lane
// owns 2 channels (uint = 2 bf16; 32 x 4B = 128B row). 2-NODE INTERLEAVE as
// agg1g. Grid 6250 x 256. Writes meanp fp32.
// ---------------------------------------------------------------------------
__global__ __launch_bounds__(256) void agg2g_kernel(const unsigned* __restrict__ es,
                                                    const int* __restrict__ rstart,
                                                    const int* __restrict__ rdeg,
                                                    const ushort* __restrict__ pb,
                                                    float* __restrict__ meanp) {
    int t = threadIdx.x;
    int l5 = t & 31;
    int nA = blockIdx.x * 16 + (t >> 5) * 2;
    int nB = nA + 1;
    int sA = rstart[nA], dA = rdeg[nA];
    int sB = rstart[nB], dB = rdeg[nB];
    const unsigned* pbu = (const unsigned*)pb;  // row = 32 uint (64 bf16)
    float a0 = 0.f, a1 = 0.f, b0 = 0.f, b1 = 0.f;
    int eA = 0, eB = 0;
    while (eA + 4 <= dA && eB + 4 <= dB) {
        int qa0 = es[sA + eA + 0], qa1 = es[sA + eA + 1];
        int qa2 = es[sA + eA + 2], qa3 = es[sA + eA + 3];
        int qb0 = es[sB + eB + 0], qb1 = es[sB + eB + 1];
        int qb2 = es[sB + eB + 2], qb3 = es[sB + eB + 3];
        unsigned ua0 = pbu[qa0 * 32 + l5], ua1 = pbu[qa1 * 32 + l5];
        unsigned ua2 = pbu[qa2 * 32 + l5], ua3 = pbu[qa3 * 32 + l5];
        unsigned ub0 = pbu[qb0 * 32 + l5], ub1 = pbu[qb1 * 32 + l5];
        unsigned ub2 = pbu[qb2 * 32 + l5], ub3 = pbu[qb3 * 32 + l5];
        a0 += bflo(ua0) + bflo(ua1) + bflo(ua2) + bflo(ua3);
        a1 += bfhi(ua0) + bfhi(ua1) + bfhi(ua2) + bfhi(ua3);
        b0 += bflo(ub0) + bflo(ub1) + bflo(ub2) + bflo(ub3);
        b1 += bfhi(ub0) + bfhi(ub1) + bfhi(ub2) + bfhi(ub3);
        eA += 4; eB += 4;
    }
    for (; eA + 4 <= dA; eA += 4) {
        int q0 = es[sA + eA + 0], q1 = es[sA + eA + 1];
        int q2 = es[sA + eA + 2], q3 = es[sA + eA + 3];
        unsigned u0 = pbu[q0 * 32 + l5], u1 = pbu[q1 * 32 + l5];
        unsigned u2 = pbu[q2 * 32 + l5], u3 = pbu[q3 * 32 + l5];
        a0 += bflo(u0) + bflo(u1) + bflo(u2) + bflo(u3);
        a1 += bfhi(u0) + bfhi(u1) + bfhi(u2) + bfhi(u3);
    }
    for (; eA < dA; ++eA) {
        unsigned u = pbu[es[sA + eA] * 32 + l5];
        a0 += bflo(u); a1 += bfhi(u);
    }
    for (; eB + 4 <= dB; eB += 4) {
        int q0 = es[sB + eB + 0], q1 = es[sB + eB + 1];
        int q2 = es[sB + eB + 2], q3 = es[sB + eB + 3];
        unsigned u0 = pbu[q0 * 32 + l5], u1 = pbu[q1 * 32 + l5];
        unsigned u2 = pbu[q2 * 32 + l5], u3 = pbu[q3 * 32 + l5];
        b0 += bflo(u0) + bflo(u1) + bflo(u2) + bflo(u3);
        b1 += bfhi(u0) + bfhi(u1) + bfhi(u2) + bfhi(u3);
    }
    for (; eB < dB; ++eB) {
        unsigned u = pbu[es[sB + eB] * 32 + l5];
        b0 += bflo(u); b1 += bfhi(u);
    }
    float invA = 1.0f / fmaxf((float)dA, 1.0f);
    float invB = 1.0f / fmaxf((float)dB, 1.0f);
    float2 oA = {a0 * invA, a1 * invA};
    float2 oB = {b0 * invB, b1 * invB};
    *(float2*)&meanp[(size_t)nA * 64 + 2 * l5] = oA;
    *(float2*)&meanp[(size_t)nB * 64 + 2 * l5] = oB;
}

// ---------------------------------------------------------------------------
// GEMM1 (MFMA): h = relu(mean@W1l + x@W1r + b1); hb = bf16(h); pb = bf16(h@W2l).
// ---------------------------------------------------------------------------
__global__ __launch_bounds__(256) void gemm1_kernel(const ushort* __restrict__ meanb,
                                                    const ushort* __restrict__ xb,
                                                    const ushort* __restrict__ w1lp,
                                                    const ushort* __restrict__ w1rp,
                                                    const float* __restrict__ b1,
                                                    const ushort* __restrict__ w2lp,
                                                    ushort* __restrict__ hb,
                                                    ushort* __restrict__ pb) {
    __shared__ ushort As[64 * 136];
    int t = threadIdx.x;
    int node0 = blockIdx.x * 64;
    int w = t >> 6, l = t & 63;
    int lrow = w * 16 + (l & 15);
    int lkq = (l >> 4) * 8;
    int cq = l & 15, rq = (l >> 4) * 4;

    f32x4 acc[8];
#pragma unroll
    for (int i = 0; i < 8; ++i) acc[i] = (f32x4){0.f, 0.f, 0.f, 0.f};

    {
        const uint4* g = (const uint4*)(meanb + (size_t)node0 * 128);
#pragma unroll
        for (int i = 0; i < 4; ++i) {
            int chunk = t + 256 * i;
            *(uint4*)&As[(chunk >> 4) * 136 + (chunk & 15) * 8] = g[chunk];
        }
    }
    __syncthreads();
#pragma unroll
    for (int kt = 0; kt < 4; ++kt) {
        bf16x8 a = *(const bf16x8*)&As[lrow * 136 + kt * 32 + lkq];
        const bf16x8* bp = (const bf16x8*)w1lp + (kt * 8) * 64 + l;
#pragma unroll
        for (int nt = 0; nt < 8; ++nt)
            acc[nt] = __builtin_amdgcn_mfma_f32_16x16x32_bf16(a, bp[nt * 64], acc[nt], 0, 0, 0);
    }
    __syncthreads();

    {
        const uint4* g = (const uint4*)(xb + (size_t)node0 * 128);
#pragma unroll
        for (int i = 0; i < 4; ++i) {
            int chunk = t + 256 * i;
            *(uint4*)&As[(chunk >> 4) * 136 + (chunk & 15) * 8] = g[chunk];
        }
    }
    __syncthreads();
#pragma unroll
    for (int kt = 0; kt < 4; ++kt) {
        bf16x8 a = *(const bf16x8*)&As[lrow * 136 + kt * 32 + lkq];
        const bf16x8* bp = (const bf16x8*)w1rp + (kt * 8) * 64 + l;
#pragma unroll
        for (int nt = 0; nt < 8; ++nt)
            acc[nt] = __builtin_amdgcn_mfma_f32_16x16x32_bf16(a, bp[nt * 64], acc[nt], 0, 0, 0);
    }
    __syncthreads();

#pragma unroll
    for (int nt = 0; nt < 8; ++nt) {
        int n = nt * 16 + cq;
        float bias = b1[n];
#pragma unroll
        for (int r = 0; r < 4; ++r) {
            float hv = fmaxf(acc[nt][r] + bias, 0.0f);
            As[(w * 16 + rq + r) * 136 + n] = f2bf(hv);
        }
    }
    __syncthreads();

    {
        uint4* g = (uint4*)(hb + (size_t)node0 * 128);
#pragma unroll
        for (int i = 0; i < 4; ++i) {
            int chunk = t + 256 * i;
            if (node0 + (chunk >> 4) < NN)
                g[chunk] = *(const uint4*)&As[(chunk >> 4) * 136 + (chunk & 15) * 8];
        }
    }

    f32x4 acc2[4];
#pragma unroll
    for (int i = 0; i < 4; ++i) acc2[i] = (f32x4){0.f, 0.f, 0.f, 0.f};
#pragma unroll
    for (int kt = 0; kt < 4; ++kt) {
        bf16x8 a = *(const bf16x8*)&As[lrow * 136 + kt * 32 + lkq];
        const bf16x8* bp = (const bf16x8*)w2lp + (kt * 4) * 64 + l;
#pragma unroll
        for (int nt = 0; nt < 4; ++nt)
            acc2[nt] = __builtin_amdgcn_mfma_f32_16x16x32_bf16(a, bp[nt * 64], acc2[nt], 0, 0, 0);
    }
    __syncthreads();

#pragma unroll
    for (int nt = 0; nt < 4; ++nt)
#pragma unroll
        for (int r = 0; r < 4; ++r)
            As[(w * 16 + rq + r) * 136 + nt * 16 + cq] = f2bf(acc2[nt][r]);
    __syncthreads();
    {
        uint4* g = (uint4*)(pb + (size_t)node0 * 64);
#pragma unroll
        for (int i = 0; i < 2; ++i) {
            int chunk = t + 256 * i;
            if (node0 + (chunk >> 3) < NN)
                g[chunk] = *(const uint4*)&As[(chunk >> 3) * 136 + (chunk & 7) * 8];
        }
    }
}

// ---------------------------------------------------------------------------
// GEMM2 (MFMA): out = meanp + hb@W2r + b2.
// ---------------------------------------------------------------------------
__global__ __launch_bounds__(256) void gemm2_kernel(const float* __restrict__ meanp,
                                                    const ushort* __restrict__ hb,
                                                    const ushort* __restrict__ w2rp,
                                                    const float* __restrict__ b2,
                                                    float* __restrict__ out) {
    __shared__ ushort As[64 * 136];
    int t = threadIdx.x;
    int node0 = blockIdx.x * 64;
    int w = t >> 6, l = t & 63;
    int lrow = w * 16 + (l & 15);
    int lkq = (l >> 4) * 8;
    int cq = l & 15, rq = (l >> 4) * 4;

    {
        const uint4* g = (const uint4*)(hb + (size_t)node0 * 128);
#pragma unroll
        for (int i = 0; i < 4; ++i) {
            int chunk = t + 256 * i;
            *(uint4*)&As[(chunk >> 4) * 136 + (chunk & 15) * 8] = g[chunk];
        }
    }
    __syncthreads();

    f32x4 acc[4];
#pragma unroll
    for (int i = 0; i < 4; ++i) acc[i] = (f32x4){0.f, 0.f, 0.f, 0.f};
#pragma unroll
    for (int kt = 0; kt < 4; ++kt) {
        bf16x8 a = *(const bf16x8*)&As[lrow * 136 + kt * 32 + lkq];
        const bf16x8* bp = (const bf16x8*)w2rp + (kt * 4) * 64 + l;
#pragma unroll
        for (int nt = 0; nt < 4; ++nt)
            acc[nt] = __builtin_amdgcn_mfma_f32_16x16x32_bf16(a, bp[nt * 64], acc[nt], 0, 0, 0);
    }

#pragma unroll
    for (int nt = 0; nt < 4; ++nt) {
        int n = nt * 16 + cq;
        float bias = b2[n];
#pragma unroll
        for (int r = 0; r < 4; ++r) {
            int row = node0 + w * 16 + rq + r;
            if (row < NN)
                out[(size_t)row * 64 + n] = acc[nt][r] + bias + meanp[(size_t)row * 64 + n];
        }
    }
}

extern "C" void kernel_launch(void* const* d_in, const int* in_sizes, int n_in,
                              void* d_out, int out_size, void* d_ws, size_t ws_size,
                              hipStream_t stream) {
    const float* x   = (const float*)d_in[0];
    const int*   ei  = (const int*)d_in[1];
    const float* W1l = (const float*)d_in[2];
    const float* W1r = (const float*)d_in[3];
    const float* b1  = (const float*)d_in[4];
    const float* W2l = (const float*)d_in[5];
    const float* W2r = (const float*)d_in[6];
    const float* b2  = (const float*)d_in[7];

    const int* src = ei;
    const int* dst = ei + NE;

    int*      ws_i   = (int*)d_ws;
    int*      cc     = ws_i + OFF_CC;
    int*      rstart = ws_i + OFF_RST;
    int*      rdeg   = ws_i + OFF_RDG;
    unsigned* stage  = (unsigned*)(ws_i + OFF_STAGE);
    ushort*   xb     = (ushort*)(ws_i + OFF_XB);
    unsigned* xf8    = (unsigned*)(ws_i + OFF_XF8);
    ushort*   pb     = (ushort*)(ws_i + OFF_XF8);   // aliases xf8 (disjoint lifetime)
    ushort*   meanb  = (ushort*)(ws_i + OFF_MEANB);
    float*    meanp  = (float*)(ws_i + OFF_MEANB);  // aliases meanb (disjoint lifetime)
    ushort*   hb     = (ushort*)(ws_i + OFF_HB);
    ushort*   w1lp   = (ushort*)(ws_i + OFF_W1LP);
    ushort*   w1rp   = (ushort*)(ws_i + OFF_W1RP);
    ushort*   w2lp   = (ushort*)(ws_i + OFF_W2LP);
    ushort*   w2rp   = (ushort*)(ws_i + OFF_W2RP);

    // Prep: zero cursors, convert x (bf16+fp8), pack weights, partition, sort.
    hipMemsetAsync(cc, 0, 1024 * sizeof(int), stream);
    cvt_kernel<<<12500, 256, 0, stream>>>(x, xb, xf8);
    pack_kernel<<<24, 256, 0, stream>>>(W1l, W1r, W2l, W2r, w1lp, w1rp, w2lp, w2rp);
    cpart_kernel<<<PBLK, 1024, 0, stream>>>(src, dst, cc, stage);
    sort_kernel<<<KB, 256, 0, stream>>>(stage, cc, rstart, rdeg);

    // Layer 1
    agg1g_kernel<<<NN / 32, 256, 0, stream>>>(stage, rstart, rdeg, xf8, meanb);
    gemm1_kernel<<<(NN + 63) / 64, 256, 0, stream>>>(meanb, xb, w1lp, w1rp, b1, w2lp, hb, pb);

    // Layer 2 (aggregation commuted past W2l)
    agg2g_kernel<<<NN / 16, 256, 0, stream>>>(stage, rstart, rdeg, pb, meanp);
    gemm2_kernel<<<(NN + 63) / 64, 256, 0, stream>>>(meanp, hb, w2rp, b2, (float*)d_out);
}

// Round 2
// 268.764 us; speedup vs baseline: 1.0009x; 1.0004x over previous
//
#include <hip/hip_runtime.h>

#define NN 100000
#define NE 1600000
#define KB 782      // coarse buckets: ceil(100000/128)
#define BSH 7       // bucket = dst >> 7; 128 nodes per bucket
#define MAXB 4096   // fixed slots per bucket (mean 2046, max ~2250 — safe)
#define PBLK 200    // cpart block-range; NE/PBLK = 8000 edges per block

// Workspace layout in 4-byte units:
#define OFF_CC    0            // 1024: per-bucket edge counts
#define OFF_RST   1024         // 100096: per-node edge-range start (global slot index)
#define OFF_RDG   101120       // 100096: per-node degree
#define OFF_STAGE 201216       // KB*MAXB: packed (dstLow<<17)|src; node-sorted src after sort_kernel
#define OFF_XB    3404288      // x bf16 [100096,128]
#define OFF_XF8   9810432      // x fp8 [100096,128]; pb bf16 [100096,64] aliases (xf8 dead after agg1g)
#define OFF_MEANB 13013504     // mean bf16 [100096,128]
#define OFF_W1LP  25825792     // packed weights bf16
#define OFF_W1RP  (25825792 + 8192)
#define OFF_W2LP  (25825792 + 16384)
#define OFF_W2RP  (25825792 + 20480)

typedef __bf16 bf16x8 __attribute__((ext_vector_type(8)));
typedef float f32x4 __attribute__((ext_vector_type(4)));
typedef float f32x2 __attribute__((ext_vector_type(2)));

static __device__ __forceinline__ ushort f2bf(float f) {
    unsigned u = __float_as_uint(f);
    return (ushort)((u + 0x7fffu + ((u >> 16) & 1u)) >> 16);
}
static __device__ __forceinline__ float bflo(unsigned u) { return __uint_as_float(u << 16); }
static __device__ __forceinline__ float bfhi(unsigned u) { return __uint_as_float(u & 0xffff0000u); }

// ---------------------------------------------------------------------------
// Fused prep: cpart (blocks [0,200)) + pack (blocks [200,224)) + cvt (rest).
// The three are mutually independent; one launch lets them fill the machine
// concurrently instead of running serially. cpart blocks go FIRST (they feed
// sort_kernel, the next dependency).
// ---------------------------------------------------------------------------
#define PREP_CPART 200
#define PREP_PACK  24
#define PREP_CVT   12500

__global__ __launch_bounds__(256) void prep_kernel(
    const float* __restrict__ x, ushort* __restrict__ xb, unsigned* __restrict__ xf8,
    const float* __restrict__ W1l, const float* __restrict__ W1r,
    const float* __restrict__ W2l, const float* __restrict__ W2r,
    ushort* __restrict__ w1lp, ushort* __restrict__ w1rp,
    ushort* __restrict__ w2lp, ushort* __restrict__ w2rp,
    const int* __restrict__ src, const int* __restrict__ dst,
    int* __restrict__ cc, unsigned* __restrict__ stage) {
    __shared__ int hist[KB];
    __shared__ int cur[KB];
    int bid = blockIdx.x;
    int t = threadIdx.x;

    if (bid >= PREP_CPART + PREP_PACK) {
        // ---- cvt: x fp32 -> xb bf16 + xf8 fp8 ----
        int i = (bid - PREP_CPART - PREP_PACK) * 256 + t;  // covers NN*128/4 = 3.2M
        float4 v = ((const float4*)x)[i];
        uint2 o;
        o.x = (unsigned)f2bf(v.x) | ((unsigned)f2bf(v.y) << 16);
        o.y = (unsigned)f2bf(v.z) | ((unsigned)f2bf(v.w) << 16);
        ((uint2*)xb)[i] = o;
        int p8 = __builtin_amdgcn_cvt_pk_fp8_f32(v.x, v.y, 0, false);
        p8 = __builtin_amdgcn_cvt_pk_fp8_f32(v.z, v.w, p8, true);
        xf8[i] = (unsigned)p8;
        return;
    }

    if (bid >= PREP_CPART) {
        // ---- pack: weights fp32 -> bf16 MFMA B-frag layout ----
        int blk = bid - PREP_CPART;
        const float* W;
        ushort* out;
        int N, frag0;
        if (blk < 8)       { W = W1l; out = w1lp; N = 128; frag0 = blk * 4; }
        else if (blk < 16) { W = W1r; out = w1rp; N = 128; frag0 = (blk - 8) * 4; }
        else if (blk < 20) { W = W2l; out = w2lp; N = 64;  frag0 = (blk - 16) * 4; }
        else               { W = W2r; out = w2rp; N = 64;  frag0 = (blk - 20) * 4; }
        int lane = t & 63;
        int frag = frag0 + (t >> 6);
        int NT = N >> 4;
        int ktile = frag / NT, ntile = frag - ktile * NT;
        int k = ktile * 32 + (lane >> 4) * 8;
        int n = ntile * 16 + (lane & 15);
        ushort tmp[8];
#pragma unroll
        for (int j = 0; j < 8; ++j) tmp[j] = f2bf(W[(k + j) * N + n]);
        uint4 o;
        o.x = (unsigned)tmp[0] | ((unsigned)tmp[1] << 16);
        o.y = (unsigned)tmp[2] | ((unsigned)tmp[3] << 16);
        o.z = (unsigned)tmp[4] | ((unsigned)tmp[5] << 16);
        o.w = (unsigned)tmp[6] | ((unsigned)tmp[7] << 16);
        *(uint4*)&out[(frag * 64 + lane) * 8] = o;
        return;
    }

    // ---- cpart: coarse partition into fixed-capacity bucket slots ----
    int e0 = bid * (NE / PBLK);
    int e1 = e0 + (NE / PBLK);
    for (int i = t; i < KB; i += 256) hist[i] = 0;
    __syncthreads();
    for (int e = e0 + t; e < e1; e += 256)
        atomicAdd(&hist[dst[e] >> BSH], 1);
    __syncthreads();
    for (int i = t; i < KB; i += 256) {
        int c = hist[i];
        cur[i] = c ? atomicAdd(&cc[i], c) : 0;
    }
    __syncthreads();
    for (int e = e0 + t; e < e1; e += 256) {
        int d = dst[e];
        int bkt = d >> BSH;
        int p = atomicAdd(&cur[bkt], 1);
        if (p < MAXB)
            stage[bkt * MAXB + p] = ((unsigned)(d & 127) << 17) | (unsigned)src[e];
    }
}

// ---------------------------------------------------------------------------
// Sort: one block per bucket. Build local CSR in LDS, write node-sorted src
// back into the stage slots, emit global rstart/rdeg.
// ---------------------------------------------------------------------------
__global__ __launch_bounds__(256) void sort_kernel(unsigned* __restrict__ stage,
                                                   const int* __restrict__ cc,
                                                   int* __restrict__ rstart,
                                                   int* __restrict__ rdeg) {
    __shared__ unsigned ssrc[MAXB];
    __shared__ int sc[128];
    __shared__ int loff[129];
    __shared__ int lcur[128];
    int t = threadIdx.x;
    int b = blockIdx.x;
    unsigned* st = stage + b * MAXB;
    int cnt = min(cc[b], MAXB);

    if (t < 128) lcur[t] = 0;
    __syncthreads();
    for (int i = t; i < cnt; i += 256) atomicAdd(&lcur[st[i] >> 17], 1);
    __syncthreads();
    if (t < 128) sc[t] = lcur[t];
    __syncthreads();
    for (int off = 1; off < 128; off <<= 1) {
        int v = (t < 128 && t >= off) ? sc[t - off] : 0;
        __syncthreads();
        if (t < 128) sc[t] += v;
        __syncthreads();
    }
    if (t < 128) {
        int excl = (t == 0) ? 0 : sc[t - 1];
        loff[t] = excl;
        lcur[t] = excl;
    }
    if (t == 127) loff[128] = sc[127];
    __syncthreads();
    for (int i = t; i < cnt; i += 256) {
        unsigned v = st[i];
        int p = atomicAdd(&lcur[v >> 17], 1);
        ssrc[p] = v & 0x1FFFFu;
    }
    __syncthreads();
    for (int i = t; i < cnt; i += 256) st[i] = ssrc[i];
    int node0 = b << BSH;
    if (t < 128 && node0 + t < NN) {
        rstart[node0 + t] = b * MAXB + loff[t];
        rdeg[node0 + t] = loff[t + 1] - loff[t];
    }
}

// ---------------------------------------------------------------------------
// Layer-1 gather (fp8, zero LDS): 16 lanes per node, lane owns 8 channels
// (uint2 = 8 fp8). 2-node interleave per group. Grid 3125 x 256.
// ---------------------------------------------------------------------------
static __device__ __forceinline__ void accum8(float* a, uint2 u) {
    f32x2 p0 = __builtin_amdgcn_cvt_pk_f32_fp8(u.x, false);
    f32x2 p1 = __builtin_amdgcn_cvt_pk_f32_fp8(u.x, true);
    f32x2 p2 = __builtin_amdgcn_cvt_pk_f32_fp8(u.y, false);
    f32x2 p3 = __builtin_amdgcn_cvt_pk_f32_fp8(u.y, true);
    a[0] += p0.x; a[1] += p0.y; a[2] += p1.x; a[3] += p1.y;
    a[4] += p2.x; a[5] += p2.y; a[6] += p3.x; a[7] += p3.y;
}

static __device__ __forceinline__ void writeRow8(ushort* __restrict__ meanb, int node,
                                                 int l4, const float* a, int deg) {
    float inv = 1.0f / fmaxf((float)deg, 1.0f);
    uint4 o;
    o.x = (unsigned)f2bf(a[0] * inv) | ((unsigned)f2bf(a[1] * inv) << 16);
    o.y = (unsigned)f2bf(a[2] * inv) | ((unsigned)f2bf(a[3] * inv) << 16);
    o.z = (unsigned)f2bf(a[4] * inv) | ((unsigned)f2bf(a[5] * inv) << 16);
    o.w = (unsigned)f2bf(a[6] * inv) | ((unsigned)f2bf(a[7] * inv) << 16);
    *(uint4*)&meanb[node * 128 + 8 * l4] = o;
}

__global__ __launch_bounds__(256) void agg1g_kernel(const unsigned* __restrict__ es,
                                                    const int* __restrict__ rstart,
                                                    const int* __restrict__ rdeg,
                                                    const unsigned* __restrict__ xf8,
                                                    ushort* __restrict__ meanb) {
    int t = threadIdx.x;
    int l4 = t & 15;
    int nA = blockIdx.x * 32 + (t >> 4) * 2;
    int nB = nA + 1;
    int sA = rstart[nA], dA = rdeg[nA];
    int sB = rstart[nB], dB = rdeg[nB];
    const uint2* xv = (const uint2*)xf8;  // row = 16 uint2 (128 fp8)
    float aA[8] = {0.f, 0.f, 0.f, 0.f, 0.f, 0.f, 0.f, 0.f};
    float aB[8] = {0.f, 0.f, 0.f, 0.f, 0.f, 0.f, 0.f, 0.f};
    int eA = 0, eB = 0;
    while (eA + 4 <= dA && eB + 4 <= dB) {
        int qa0 = es[sA + eA + 0], qa1 = es[sA + eA + 1];
        int qa2 = es[sA + eA + 2], qa3 = es[sA + eA + 3];
        int qb0 = es[sB + eB + 0], qb1 = es[sB + eB + 1];
        int qb2 = es[sB + eB + 2], qb3 = es[sB + eB + 3];
        uint2 ua0 = xv[qa0 * 16 + l4], ua1 = xv[qa1 * 16 + l4];
        uint2 ua2 = xv[qa2 * 16 + l4], ua3 = xv[qa3 * 16 + l4];
        uint2 ub0 = xv[qb0 * 16 + l4], ub1 = xv[qb1 * 16 + l4];
        uint2 ub2 = xv[qb2 * 16 + l4], ub3 = xv[qb3 * 16 + l4];
        accum8(aA, ua0); accum8(aA, ua1); accum8(aA, ua2); accum8(aA, ua3);
        accum8(aB, ub0); accum8(aB, ub1); accum8(aB, ub2); accum8(aB, ub3);
        eA += 4; eB += 4;
    }
    for (; eA + 4 <= dA; eA += 4) {
        int q0 = es[sA + eA + 0], q1 = es[sA + eA + 1];
        int q2 = es[sA + eA + 2], q3 = es[sA + eA + 3];
        uint2 u0 = xv[q0 * 16 + l4], u1 = xv[q1 * 16 + l4];
        uint2 u2 = xv[q2 * 16 + l4], u3 = xv[q3 * 16 + l4];
        accum8(aA, u0); accum8(aA, u1); accum8(aA, u2); accum8(aA, u3);
    }
    for (; eA < dA; ++eA) accum8(aA, xv[es[sA + eA] * 16 + l4]);
    for (; eB + 4 <= dB; eB += 4) {
        int q0 = es[sB + eB + 0], q1 = es[sB + eB + 1];
        int q2 = es[sB + eB + 2], q3 = es[sB + eB + 3];
        uint2 u0 = xv[q0 * 16 + l4], u1 = xv[q1 * 16 + l4];
        uint2 u2 = xv[q2 * 16 + l4], u3 = xv[q3 * 16 + l4];
        accum8(aB, u0); accum8(aB, u1); accum8(aB, u2); accum8(aB, u3);
    }
    for (; eB < dB; ++eB) accum8(aB, xv[es[sB + eB] * 16 + l4]);

    writeRow8(meanb, nA, l4, aA, dA);
    writeRow8(meanb, nB, l4, aB, dB);
}

// ---------------------------------------------------------------------------
// Layer-2 gather + final combine: gathers pb (bf16), means, then
// out[node] = partial_out[node] (h@W2r + b2, from gemm1) + mean.
// 32 lanes per node, 2-node interleave. Grid 6250 x 256.
// ---------------------------------------------------------------------------
__global__ __launch_bounds__(256) void agg2g_kernel(const unsigned* __restrict__ es,
                                                    const int* __restrict__ rstart,
                                                    const int* __restrict__ rdeg,
                                                    const ushort* __restrict__ pb,
                                                    float* __restrict__ out) {
    int t = threadIdx.x;
    int l5 = t & 31;
    int nA = blockIdx.x * 16 + (t >> 5) * 2;
    int nB = nA + 1;
    int sA = rstart[nA], dA = rdeg[nA];
    int sB = rstart[nB], dB = rdeg[nB];
    // Issue the partial-out reads early; they're coalesced and hide under the gather.
    float2 pA = *(const float2*)&out[(size_t)nA * 64 + 2 * l5];
    float2 pB = *(const float2*)&out[(size_t)nB * 64 + 2 * l5];
    const unsigned* pbu = (const unsigned*)pb;  // row = 32 uint (64 bf16)
    float a0 = 0.f, a1 = 0.f, b0 = 0.f, b1 = 0.f;
    int eA = 0, eB = 0;
    while (eA + 4 <= dA && eB + 4 <= dB) {
        int qa0 = es[sA + eA + 0], qa1 = es[sA + eA + 1];
        int qa2 = es[sA + eA + 2], qa3 = es[sA + eA + 3];
        int qb0 = es[sB + eB + 0], qb1 = es[sB + eB + 1];
        int qb2 = es[sB + eB + 2], qb3 = es[sB + eB + 3];
        unsigned ua0 = pbu[qa0 * 32 + l5], ua1 = pbu[qa1 * 32 + l5];
        unsigned ua2 = pbu[qa2 * 32 + l5], ua3 = pbu[qa3 * 32 + l5];
        unsigned ub0 = pbu[qb0 * 32 + l5], ub1 = pbu[qb1 * 32 + l5];
        unsigned ub2 = pbu[qb2 * 32 + l5], ub3 = pbu[qb3 * 32 + l5];
        a0 += bflo(ua0) + bflo(ua1) + bflo(ua2) + bflo(ua3);
        a1 += bfhi(ua0) + bfhi(ua1) + bfhi(ua2) + bfhi(ua3);
        b0 += bflo(ub0) + bflo(ub1) + bflo(ub2) + bflo(ub3);
        b1 += bfhi(ub0) + bfhi(ub1) + bfhi(ub2) + bfhi(ub3);
        eA += 4; eB += 4;
    }
    for (; eA + 4 <= dA; eA += 4) {
        int q0 = es[sA + eA + 0], q1 = es[sA + eA + 1];
        int q2 = es[sA + eA + 2], q3 = es[sA + eA + 3];
        unsigned u0 = pbu[q0 * 32 + l5], u1 = pbu[q1 * 32 + l5];
        unsigned u2 = pbu[q2 * 32 + l5], u3 = pbu[q3 * 32 + l5];
        a0 += bflo(u0) + bflo(u1) + bflo(u2) + bflo(u3);
        a1 += bfhi(u0) + bfhi(u1) + bfhi(u2) + bfhi(u3);
    }
    for (; eA < dA; ++eA) {
        unsigned u = pbu[es[sA + eA] * 32 + l5];
        a0 += bflo(u); a1 += bfhi(u);
    }
    for (; eB + 4 <= dB; eB += 4) {
        int q0 = es[sB + eB + 0], q1 = es[sB + eB + 1];
        int q2 = es[sB + eB + 2], q3 = es[sB + eB + 3];
        unsigned u0 = pbu[q0 * 32 + l5], u1 = pbu[q1 * 32 + l5];
        unsigned u2 = pbu[q2 * 32 + l5], u3 = pbu[q3 * 32 + l5];
        b0 += bflo(u0) + bflo(u1) + bflo(u2) + bflo(u3);
        b1 += bfhi(u0) + bfhi(u1) + bfhi(u2) + bfhi(u3);
    }
    for (; eB < dB; ++eB) {
        unsigned u = pbu[es[sB + eB] * 32 + l5];
        b0 += bflo(u); b1 += bfhi(u);
    }
    float invA = 1.0f / fmaxf((float)dA, 1.0f);
    float invB = 1.0f / fmaxf((float)dB, 1.0f);
    float2 oA = {pA.x + a0 * invA, pA.y + a1 * invA};
    float2 oB = {pB.x + b0 * invB, pB.y + b1 * invB};
    *(float2*)&out[(size_t)nA * 64 + 2 * l5] = oA;
    *(float2*)&out[(size_t)nB * 64 + 2 * l5] = oB;
}

// ---------------------------------------------------------------------------
// GEMM1 fused (MFMA): h = relu(mean@W1l + x@W1r + b1);
//   pb  = bf16(h@W2l)         (for the layer-2 gather)
//   out = h@W2r + b2          (partial final output; agg2g adds the mean)
// hb is never materialized — gemm2 is gone.
// ---------------------------------------------------------------------------
__global__ __launch_bounds__(256) void gemm1_kernel(const ushort* __restrict__ meanb,
                                                    const ushort* __restrict__ xb,
                                                    const ushort* __restrict__ w1lp,
                                                    const ushort* __restrict__ w1rp,
                                                    const float* __restrict__ b1,
                                                    const ushort* __restrict__ w2lp,
                                                    const ushort* __restrict__ w2rp,
                                                    const float* __restrict__ b2,
                                                    ushort* __restrict__ pb,
                                                    float* __restrict__ out) {
    __shared__ ushort As[64 * 136];
    int t = threadIdx.x;
    int node0 = blockIdx.x * 64;
    int w = t >> 6, l = t & 63;
    int lrow = w * 16 + (l & 15);
    int lkq = (l >> 4) * 8;
    int cq = l & 15, rq = (l >> 4) * 4;

    f32x4 acc[8];
#pragma unroll
    for (int i = 0; i < 8; ++i) acc[i] = (f32x4){0.f, 0.f, 0.f, 0.f};

    {
        const uint4* g = (const uint4*)(meanb + (size_t)node0 * 128);
#pragma unroll
        for (int i = 0; i < 4; ++i) {
            int chunk = t + 256 * i;
            *(uint4*)&As[(chunk >> 4) * 136 + (chunk & 15) * 8] = g[chunk];
        }
    }
    __syncthreads();
#pragma unroll
    for (int kt = 0; kt < 4; ++kt) {
        bf16x8 a = *(const bf16x8*)&As[lrow * 136 + kt * 32 + lkq];
        const bf16x8* bp = (const bf16x8*)w1lp + (kt * 8) * 64 + l;
#pragma unroll
        for (int nt = 0; nt < 8; ++nt)
            acc[nt] = __builtin_amdgcn_mfma_f32_16x16x32_bf16(a, bp[nt * 64], acc[nt], 0, 0, 0);
    }
    __syncthreads();

    {
        const uint4* g = (const uint4*)(xb + (size_t)node0 * 128);
#pragma unroll
        for (int i = 0; i < 4; ++i) {
            int chunk = t + 256 * i;
            *(uint4*)&As[(chunk >> 4) * 136 + (chunk & 15) * 8] = g[chunk];
        }
    }
    __syncthreads();
#pragma unroll
    for (int kt = 0; kt < 4; ++kt) {
        bf16x8 a = *(const bf16x8*)&As[lrow * 136 + kt * 32 + lkq];
        const bf16x8* bp = (const bf16x8*)w1rp + (kt * 8) * 64 + l;
#pragma unroll
        for (int nt = 0; nt < 8; ++nt)
            acc[nt] = __builtin_amdgcn_mfma_f32_16x16x32_bf16(a, bp[nt * 64], acc[nt], 0, 0, 0);
    }
    __syncthreads();

    // h (relu + bias) back into As as bf16.
#pragma unroll
    for (int nt = 0; nt < 8; ++nt) {
        int n = nt * 16 + cq;
        float bias = b1[n];
#pragma unroll
        for (int r = 0; r < 4; ++r) {
            float hv = fmaxf(acc[nt][r] + bias, 0.0f);
            As[(w * 16 + rq + r) * 136 + n] = f2bf(hv);
        }
    }
    __syncthreads();

    // Both second-layer products from the same h fragments.
    f32x4 acc2[4];  // h@W2l -> pb
    f32x4 acc3[4];  // h@W2r -> partial out
#pragma unroll
    for (int i = 0; i < 4; ++i) {
        acc2[i] = (f32x4){0.f, 0.f, 0.f, 0.f};
        acc3[i] = (f32x4){0.f, 0.f, 0.f, 0.f};
    }
#pragma unroll
    for (int kt = 0; kt < 4; ++kt) {
        bf16x8 a = *(const bf16x8*)&As[lrow * 136 + kt * 32 + lkq];
        const bf16x8* bpl = (const bf16x8*)w2lp + (kt * 4) * 64 + l;
        const bf16x8* bpr = (const bf16x8*)w2rp + (kt * 4) * 64 + l;
#pragma unroll
        for (int nt = 0; nt < 4; ++nt) {
            acc2[nt] = __builtin_amdgcn_mfma_f32_16x16x32_bf16(a, bpl[nt * 64], acc2[nt], 0, 0, 0);
            acc3[nt] = __builtin_amdgcn_mfma_f32_16x16x32_bf16(a, bpr[nt * 64], acc3[nt], 0, 0, 0);
        }
    }

    // Partial out = h@W2r + b2, straight from accumulators.
#pragma unroll
    for (int nt = 0; nt < 4; ++nt) {
        int n = nt * 16 + cq;
        float bias = b2[n];
#pragma unroll
        for (int r = 0; r < 4; ++r) {
            int row = node0 + w * 16 + rq + r;
            if (row < NN)
                out[(size_t)row * 64 + n] = acc3[nt][r] + bias;
        }
    }

    // pb = bf16(h@W2l) via LDS repack for vectorized store.
    __syncthreads();
#pragma unroll
    for (int nt = 0; nt < 4; ++nt)
#pragma unroll
        for (int r = 0; r < 4; ++r)
            As[(w * 16 + rq + r) * 136 + nt * 16 + cq] = f2bf(acc2[nt][r]);
    __syncthreads();
    {
        uint4* g = (uint4*)(pb + (size_t)node0 * 64);
#pragma unroll
        for (int i = 0; i < 2; ++i) {
            int chunk = t + 256 * i;
            if (node0 + (chunk >> 3) < NN)
                g[chunk] = *(const uint4*)&As[(chunk >> 3) * 136 + (chunk & 7) * 8];
        }
    }
}

extern "C" void kernel_launch(void* const* d_in, const int* in_sizes, int n_in,
                              void* d_out, int out_size, void* d_ws, size_t ws_size,
                              hipStream_t stream) {
    const float* x   = (const float*)d_in[0];
    const int*   ei  = (const int*)d_in[1];
    const float* W1l = (const float*)d_in[2];
    const float* W1r = (const float*)d_in[3];
    const float* b1  = (const float*)d_in[4];
    const float* W2l = (const float*)d_in[5];
    const float* W2r = (const float*)d_in[6];
    const float* b2  = (const float*)d_in[7];

    const int* src = ei;
    const int* dst = ei + NE;

    int*      ws_i   = (int*)d_ws;
    int*      cc     = ws_i + OFF_CC;
    int*      rstart = ws_i + OFF_RST;
    int*      rdeg   = ws_i + OFF_RDG;
    unsigned* stage  = (unsigned*)(ws_i + OFF_STAGE);
    ushort*   xb     = (ushort*)(ws_i + OFF_XB);
    unsigned* xf8    = (unsigned*)(ws_i + OFF_XF8);
    ushort*   pb     = (ushort*)(ws_i + OFF_XF8);   // aliases xf8 (disjoint lifetime)
    ushort*   meanb  = (ushort*)(ws_i + OFF_MEANB);
    ushort*   w1lp   = (ushort*)(ws_i + OFF_W1LP);
    ushort*   w1rp   = (ushort*)(ws_i + OFF_W1RP);
    ushort*   w2lp   = (ushort*)(ws_i + OFF_W2LP);
    ushort*   w2rp   = (ushort*)(ws_i + OFF_W2RP);

    hipMemsetAsync(cc, 0, 1024 * sizeof(int), stream);

    // Fused prep: cpart + pack + cvt in one concurrent launch.
    prep_kernel<<<PREP_CPART + PREP_PACK + PREP_CVT, 256, 0, stream>>>(
        x, xb, xf8, W1l, W1r, W2l, W2r, w1lp, w1rp, w2lp, w2rp, src, dst, cc, stage);
    sort_kernel<<<KB, 256, 0, stream>>>(stage, cc, rstart, rdeg);

    // Layer 1 + both second-layer products (gemm2 folded in).
    agg1g_kernel<<<NN / 32, 256, 0, stream>>>(stage, rstart, rdeg, xf8, meanb);
    gemm1_kernel<<<(NN + 63) / 64, 256, 0, stream>>>(meanb, xb, w1lp, w1rp, b1,
                                                     w2lp, w2rp, b2, pb, (float*)d_out);

    // Layer 2: gather pb, mean, add into partial out.
    agg2g_kernel<<<NN / 16, 256, 0, stream>>>(stage, rstart, rdeg, pb, (float*)d_out);
}

// Round 3
// 251.425 us; speedup vs baseline: 1.0700x; 1.0690x over previous
//
#include <hip/hip_runtime.h>

#define NN 100000
#define NE 1600000
#define KB 782      // coarse buckets: ceil(100000/128)
#define BSH 7       // bucket = dst >> 7; 128 nodes per bucket
#define MAXB 4096   // fixed slots per bucket (mean 2046, max ~2250 — safe)
#define PBLK 200    // cpart block-range; NE/PBLK = 8000 edges per block

// Workspace layout in 4-byte units:
#define OFF_CC    0            // 1024: per-bucket edge counts
#define OFF_RST   1024         // 100096: per-node edge-range start (global slot index)
#define OFF_RDG   101120       // 100096: per-node degree
#define OFF_STAGE 201216       // KB*MAXB: packed (dstLow<<17)|src; node-sorted src after sort_kernel
#define OFF_XB    3404288      // x bf16 [100096,128]
#define OFF_XF8   9810432      // x fp8 [100096,128]; pb bf16 [100096,64] aliases (xf8 dead after agg1g)
#define OFF_MEANB 13013504     // mean bf16 [100096,128]
#define OFF_W1LP  25825792     // packed weights bf16
#define OFF_W1RP  (25825792 + 8192)
#define OFF_W2LP  (25825792 + 16384)
#define OFF_W2RP  (25825792 + 20480)

typedef __bf16 bf16x8 __attribute__((ext_vector_type(8)));
typedef float f32x4 __attribute__((ext_vector_type(4)));
typedef float f32x2 __attribute__((ext_vector_type(2)));

static __device__ __forceinline__ ushort f2bf(float f) {
    unsigned u = __float_as_uint(f);
    return (ushort)((u + 0x7fffu + ((u >> 16) & 1u)) >> 16);
}
static __device__ __forceinline__ float bflo(unsigned u) { return __uint_as_float(u << 16); }
static __device__ __forceinline__ float bfhi(unsigned u) { return __uint_as_float(u & 0xffff0000u); }

// ---------------------------------------------------------------------------
// Fused prep v2 (1024 threads/block):
//   blocks [0,200)    : cpart at FULL 1024 threads (round-2 ran these at 256
//                       threads -> 4x less parallelism -> 62 us straggle).
//   blocks [200,206)  : pack, as 4 virtual 256-thread sub-blocks per block.
//   blocks [206,3331) : cvt, 1024 float4 per block (3125*1024 = 3.2M exact).
// cpart blocks first: they gate sort_kernel, the next dependency.
// ---------------------------------------------------------------------------
#define PREP_CPART 200
#define PREP_PACKB 6      // 6 blocks x 4 virtual = 24 pack sub-blocks
#define PREP_CVT   3125
#define PREP_GRID  (PREP_CPART + PREP_PACKB + PREP_CVT)

__global__ __launch_bounds__(1024) void prep_kernel(
    const float* __restrict__ x, ushort* __restrict__ xb, unsigned* __restrict__ xf8,
    const float* __restrict__ W1l, const float* __restrict__ W1r,
    const float* __restrict__ W2l, const float* __restrict__ W2r,
    ushort* __restrict__ w1lp, ushort* __restrict__ w1rp,
    ushort* __restrict__ w2lp, ushort* __restrict__ w2rp,
    const int* __restrict__ src, const int* __restrict__ dst,
    int* __restrict__ cc, unsigned* __restrict__ stage) {
    __shared__ int hist[KB];
    __shared__ int cur[KB];
    int bid = blockIdx.x;
    int t = threadIdx.x;

    if (bid >= PREP_CPART + PREP_PACKB) {
        // ---- cvt: x fp32 -> xb bf16 + xf8 fp8 ----
        int i = (bid - PREP_CPART - PREP_PACKB) * 1024 + t;  // [0, 3.2M)
        float4 v = ((const float4*)x)[i];
        uint2 o;
        o.x = (unsigned)f2bf(v.x) | ((unsigned)f2bf(v.y) << 16);
        o.y = (unsigned)f2bf(v.z) | ((unsigned)f2bf(v.w) << 16);
        ((uint2*)xb)[i] = o;
        int p8 = __builtin_amdgcn_cvt_pk_fp8_f32(v.x, v.y, 0, false);
        p8 = __builtin_amdgcn_cvt_pk_fp8_f32(v.z, v.w, p8, true);
        xf8[i] = (unsigned)p8;
        return;
    }

    if (bid >= PREP_CPART) {
        // ---- pack: weights fp32 -> bf16 MFMA B-frag layout ----
        int vb = (bid - PREP_CPART) * 4 + (t >> 8);  // virtual 256-thread block [0,24)
        int vt = t & 255;
        const float* W;
        ushort* out;
        int N, frag0;
        if (vb < 8)       { W = W1l; out = w1lp; N = 128; frag0 = vb * 4; }
        else if (vb < 16) { W = W1r; out = w1rp; N = 128; frag0 = (vb - 8) * 4; }
        else if (vb < 20) { W = W2l; out = w2lp; N = 64;  frag0 = (vb - 16) * 4; }
        else              { W = W2r; out = w2rp; N = 64;  frag0 = (vb - 20) * 4; }
        int lane = vt & 63;
        int frag = frag0 + (vt >> 6);
        int NT = N >> 4;
        int ktile = frag / NT, ntile = frag - ktile * NT;
        int k = ktile * 32 + (lane >> 4) * 8;
        int n = ntile * 16 + (lane & 15);
        ushort tmp[8];
#pragma unroll
        for (int j = 0; j < 8; ++j) tmp[j] = f2bf(W[(k + j) * N + n]);
        uint4 o;
        o.x = (unsigned)tmp[0] | ((unsigned)tmp[1] << 16);
        o.y = (unsigned)tmp[2] | ((unsigned)tmp[3] << 16);
        o.z = (unsigned)tmp[4] | ((unsigned)tmp[5] << 16);
        o.w = (unsigned)tmp[6] | ((unsigned)tmp[7] << 16);
        *(uint4*)&out[(frag * 64 + lane) * 8] = o;
        return;
    }

    // ---- cpart: coarse partition, full 1024-thread blocks ----
    int e0 = bid * (NE / PBLK);
    int e1 = e0 + (NE / PBLK);
    for (int i = t; i < KB; i += 1024) hist[i] = 0;
    __syncthreads();
    for (int e = e0 + t; e < e1; e += 1024)
        atomicAdd(&hist[dst[e] >> BSH], 1);
    __syncthreads();
    for (int i = t; i < KB; i += 1024) {
        int c = hist[i];
        cur[i] = c ? atomicAdd(&cc[i], c) : 0;
    }
    __syncthreads();
    for (int e = e0 + t; e < e1; e += 1024) {
        int d = dst[e];
        int bkt = d >> BSH;
        int p = atomicAdd(&cur[bkt], 1);
        if (p < MAXB)
            stage[bkt * MAXB + p] = ((unsigned)(d & 127) << 17) | (unsigned)src[e];
    }
}

// ---------------------------------------------------------------------------
// Sort: one block per bucket. Build local CSR in LDS, write node-sorted src
// back into the stage slots, emit global rstart/rdeg.
// ---------------------------------------------------------------------------
__global__ __launch_bounds__(256) void sort_kernel(unsigned* __restrict__ stage,
                                                   const int* __restrict__ cc,
                                                   int* __restrict__ rstart,
                                                   int* __restrict__ rdeg) {
    __shared__ unsigned ssrc[MAXB];
    __shared__ int sc[128];
    __shared__ int loff[129];
    __shared__ int lcur[128];
    int t = threadIdx.x;
    int b = blockIdx.x;
    unsigned* st = stage + b * MAXB;
    int cnt = min(cc[b], MAXB);

    if (t < 128) lcur[t] = 0;
    __syncthreads();
    for (int i = t; i < cnt; i += 256) atomicAdd(&lcur[st[i] >> 17], 1);
    __syncthreads();
    if (t < 128) sc[t] = lcur[t];
    __syncthreads();
    for (int off = 1; off < 128; off <<= 1) {
        int v = (t < 128 && t >= off) ? sc[t - off] : 0;
        __syncthreads();
        if (t < 128) sc[t] += v;
        __syncthreads();
    }
    if (t < 128) {
        int excl = (t == 0) ? 0 : sc[t - 1];
        loff[t] = excl;
        lcur[t] = excl;
    }
    if (t == 127) loff[128] = sc[127];
    __syncthreads();
    for (int i = t; i < cnt; i += 256) {
        unsigned v = st[i];
        int p = atomicAdd(&lcur[v >> 17], 1);
        ssrc[p] = v & 0x1FFFFu;
    }
    __syncthreads();
    for (int i = t; i < cnt; i += 256) st[i] = ssrc[i];
    int node0 = b << BSH;
    if (t < 128 && node0 + t < NN) {
        rstart[node0 + t] = b * MAXB + loff[t];
        rdeg[node0 + t] = loff[t + 1] - loff[t];
    }
}

// ---------------------------------------------------------------------------
// Layer-1 gather (fp8, zero LDS): 16 lanes per node, lane owns 8 channels
// (uint2 = 8 fp8). 2-node interleave per group. Grid 3125 x 256.
// ---------------------------------------------------------------------------
static __device__ __forceinline__ void accum8(float* a, uint2 u) {
    f32x2 p0 = __builtin_amdgcn_cvt_pk_f32_fp8(u.x, false);
    f32x2 p1 = __builtin_amdgcn_cvt_pk_f32_fp8(u.x, true);
    f32x2 p2 = __builtin_amdgcn_cvt_pk_f32_fp8(u.y, false);
    f32x2 p3 = __builtin_amdgcn_cvt_pk_f32_fp8(u.y, true);
    a[0] += p0.x; a[1] += p0.y; a[2] += p1.x; a[3] += p1.y;
    a[4] += p2.x; a[5] += p2.y; a[6] += p3.x; a[7] += p3.y;
}

static __device__ __forceinline__ void writeRow8(ushort* __restrict__ meanb, int node,
                                                 int l4, const float* a, int deg) {
    float inv = 1.0f / fmaxf((float)deg, 1.0f);
    uint4 o;
    o.x = (unsigned)f2bf(a[0] * inv) | ((unsigned)f2bf(a[1] * inv) << 16);
    o.y = (unsigned)f2bf(a[2] * inv) | ((unsigned)f2bf(a[3] * inv) << 16);
    o.z = (unsigned)f2bf(a[4] * inv) | ((unsigned)f2bf(a[5] * inv) << 16);
    o.w = (unsigned)f2bf(a[6] * inv) | ((unsigned)f2bf(a[7] * inv) << 16);
    *(uint4*)&meanb[node * 128 + 8 * l4] = o;
}

__global__ __launch_bounds__(256) void agg1g_kernel(const unsigned* __restrict__ es,
                                                    const int* __restrict__ rstart,
                                                    const int* __restrict__ rdeg,
                                                    const unsigned* __restrict__ xf8,
                                                    ushort* __restrict__ meanb) {
    int t = threadIdx.x;
    int l4 = t & 15;
    int nA = blockIdx.x * 32 + (t >> 4) * 2;
    int nB = nA + 1;
    int sA = rstart[nA], dA = rdeg[nA];
    int sB = rstart[nB], dB = rdeg[nB];
    const uint2* xv = (const uint2*)xf8;  // row = 16 uint2 (128 fp8)
    float aA[8] = {0.f, 0.f, 0.f, 0.f, 0.f, 0.f, 0.f, 0.f};
    float aB[8] = {0.f, 0.f, 0.f, 0.f, 0.f, 0.f, 0.f, 0.f};
    int eA = 0, eB = 0;
    while (eA + 4 <= dA && eB + 4 <= dB) {
        int qa0 = es[sA + eA + 0], qa1 = es[sA + eA + 1];
        int qa2 = es[sA + eA + 2], qa3 = es[sA + eA + 3];
        int qb0 = es[sB + eB + 0], qb1 = es[sB + eB + 1];
        int qb2 = es[sB + eB + 2], qb3 = es[sB + eB + 3];
        uint2 ua0 = xv[qa0 * 16 + l4], ua1 = xv[qa1 * 16 + l4];
        uint2 ua2 = xv[qa2 * 16 + l4], ua3 = xv[qa3 * 16 + l4];
        uint2 ub0 = xv[qb0 * 16 + l4], ub1 = xv[qb1 * 16 + l4];
        uint2 ub2 = xv[qb2 * 16 + l4], ub3 = xv[qb3 * 16 + l4];
        accum8(aA, ua0); accum8(aA, ua1); accum8(aA, ua2); accum8(aA, ua3);
        accum8(aB, ub0); accum8(aB, ub1); accum8(aB, ub2); accum8(aB, ub3);
        eA += 4; eB += 4;
    }
    for (; eA + 4 <= dA; eA += 4) {
        int q0 = es[sA + eA + 0], q1 = es[sA + eA + 1];
        int q2 = es[sA + eA + 2], q3 = es[sA + eA + 3];
        uint2 u0 = xv[q0 * 16 + l4], u1 = xv[q1 * 16 + l4];
        uint2 u2 = xv[q2 * 16 + l4], u3 = xv[q3 * 16 + l4];
        accum8(aA, u0); accum8(aA, u1); accum8(aA, u2); accum8(aA, u3);
    }
    for (; eA < dA; ++eA) accum8(aA, xv[es[sA + eA] * 16 + l4]);
    for (; eB + 4 <= dB; eB += 4) {
        int q0 = es[sB + eB + 0], q1 = es[sB + eB + 1];
        int q2 = es[sB + eB + 2], q3 = es[sB + eB + 3];
        uint2 u0 = xv[q0 * 16 + l4], u1 = xv[q1 * 16 + l4];
        uint2 u2 = xv[q2 * 16 + l4], u3 = xv[q3 * 16 + l4];
        accum8(aB, u0); accum8(aB, u1); accum8(aB, u2); accum8(aB, u3);
    }
    for (; eB < dB; ++eB) accum8(aB, xv[es[sB + eB] * 16 + l4]);

    writeRow8(meanb, nA, l4, aA, dA);
    writeRow8(meanb, nB, l4, aB, dB);
}

// ---------------------------------------------------------------------------
// Layer-2 gather + final combine: gathers pb (bf16), means, then
// out[node] = partial_out[node] (h@W2r + b2, from gemm1) + mean.
// 32 lanes per node, 2-node interleave. Grid 6250 x 256.
// ---------------------------------------------------------------------------
__global__ __launch_bounds__(256) void agg2g_kernel(const unsigned* __restrict__ es,
                                                    const int* __restrict__ rstart,
                                                    const int* __restrict__ rdeg,
                                                    const ushort* __restrict__ pb,
                                                    float* __restrict__ out) {
    int t = threadIdx.x;
    int l5 = t & 31;
    int nA = blockIdx.x * 16 + (t >> 5) * 2;
    int nB = nA + 1;
    int sA = rstart[nA], dA = rdeg[nA];
    int sB = rstart[nB], dB = rdeg[nB];
    // Coalesced partial-out reads issued early; hide under the gather.
    float2 pA = *(const float2*)&out[(size_t)nA * 64 + 2 * l5];
    float2 pB = *(const float2*)&out[(size_t)nB * 64 + 2 * l5];
    const unsigned* pbu = (const unsigned*)pb;  // row = 32 uint (64 bf16)
    float a0 = 0.f, a1 = 0.f, b0 = 0.f, b1 = 0.f;
    int eA = 0, eB = 0;
    while (eA + 4 <= dA && eB + 4 <= dB) {
        int qa0 = es[sA + eA + 0], qa1 = es[sA + eA + 1];
        int qa2 = es[sA + eA + 2], qa3 = es[sA + eA + 3];
        int qb0 = es[sB + eB + 0], qb1 = es[sB + eB + 1];
        int qb2 = es[sB + eB + 2], qb3 = es[sB + eB + 3];
        unsigned ua0 = pbu[qa0 * 32 + l5], ua1 = pbu[qa1 * 32 + l5];
        unsigned ua2 = pbu[qa2 * 32 + l5], ua3 = pbu[qa3 * 32 + l5];
        unsigned ub0 = pbu[qb0 * 32 + l5], ub1 = pbu[qb1 * 32 + l5];
        unsigned ub2 = pbu[qb2 * 32 + l5], ub3 = pbu[qb3 * 32 + l5];
        a0 += bflo(ua0) + bflo(ua1) + bflo(ua2) + bflo(ua3);
        a1 += bfhi(ua0) + bfhi(ua1) + bfhi(ua2) + bfhi(ua3);
        b0 += bflo(ub0) + bflo(ub1) + bflo(ub2) + bflo(ub3);
        b1 += bfhi(ub0) + bfhi(ub1) + bfhi(ub2) + bfhi(ub3);
        eA += 4; eB += 4;
    }
    for (; eA + 4 <= dA; eA += 4) {
        int q0 = es[sA + eA + 0], q1 = es[sA + eA + 1];
        int q2 = es[sA + eA + 2], q3 = es[sA + eA + 3];
        unsigned u0 = pbu[q0 * 32 + l5], u1 = pbu[q1 * 32 + l5];
        unsigned u2 = pbu[q2 * 32 + l5], u3 = pbu[q3 * 32 + l5];
        a0 += bflo(u0) + bflo(u1) + bflo(u2) + bflo(u3);
        a1 += bfhi(u0) + bfhi(u1) + bfhi(u2) + bfhi(u3);
    }
    for (; eA < dA; ++eA) {
        unsigned u = pbu[es[sA + eA] * 32 + l5];
        a0 += bflo(u); a1 += bfhi(u);
    }
    for (; eB + 4 <= dB; eB += 4) {
        int q0 = es[sB + eB + 0], q1 = es[sB + eB + 1];
        int q2 = es[sB + eB + 2], q3 = es[sB + eB + 3];
        unsigned u0 = pbu[q0 * 32 + l5], u1 = pbu[q1 * 32 + l5];
        unsigned u2 = pbu[q2 * 32 + l5], u3 = pbu[q3 * 32 + l5];
        b0 += bflo(u0) + bflo(u1) + bflo(u2) + bflo(u3);
        b1 += bfhi(u0) + bfhi(u1) + bfhi(u2) + bfhi(u3);
    }
    for (; eB < dB; ++eB) {
        unsigned u = pbu[es[sB + eB] * 32 + l5];
        b0 += bflo(u); b1 += bfhi(u);
    }
    float invA = 1.0f / fmaxf((float)dA, 1.0f);
    float invB = 1.0f / fmaxf((float)dB, 1.0f);
    float2 oA = {pA.x + a0 * invA, pA.y + a1 * invA};
    float2 oB = {pB.x + b0 * invB, pB.y + b1 * invB};
    *(float2*)&out[(size_t)nA * 64 + 2 * l5] = oA;
    *(float2*)&out[(size_t)nB * 64 + 2 * l5] = oB;
}

// ---------------------------------------------------------------------------
// GEMM1 fused (MFMA): h = relu(mean@W1l + x@W1r + b1);
//   pb  = bf16(h@W2l)         (for the layer-2 gather)
//   out = h@W2r + b2          (partial final output; agg2g adds the mean)
// ---------------------------------------------------------------------------
__global__ __launch_bounds__(256) void gemm1_kernel(const ushort* __restrict__ meanb,
                                                    const ushort* __restrict__ xb,
                                                    const ushort* __restrict__ w1lp,
                                                    const ushort* __restrict__ w1rp,
                                                    const float* __restrict__ b1,
                                                    const ushort* __restrict__ w2lp,
                                                    const ushort* __restrict__ w2rp,
                                                    const float* __restrict__ b2,
                                                    ushort* __restrict__ pb,
                                                    float* __restrict__ out) {
    __shared__ ushort As[64 * 136];
    int t = threadIdx.x;
    int node0 = blockIdx.x * 64;
    int w = t >> 6, l = t & 63;
    int lrow = w * 16 + (l & 15);
    int lkq = (l >> 4) * 8;
    int cq = l & 15, rq = (l >> 4) * 4;

    f32x4 acc[8];
#pragma unroll
    for (int i = 0; i < 8; ++i) acc[i] = (f32x4){0.f, 0.f, 0.f, 0.f};

    {
        const uint4* g = (const uint4*)(meanb + (size_t)node0 * 128);
#pragma unroll
        for (int i = 0; i < 4; ++i) {
            int chunk = t + 256 * i;
            *(uint4*)&As[(chunk >> 4) * 136 + (chunk & 15) * 8] = g[chunk];
        }
    }
    __syncthreads();
#pragma unroll
    for (int kt = 0; kt < 4; ++kt) {
        bf16x8 a = *(const bf16x8*)&As[lrow * 136 + kt * 32 + lkq];
        const bf16x8* bp = (const bf16x8*)w1lp + (kt * 8) * 64 + l;
#pragma unroll
        for (int nt = 0; nt < 8; ++nt)
            acc[nt] = __builtin_amdgcn_mfma_f32_16x16x32_bf16(a, bp[nt * 64], acc[nt], 0, 0, 0);
    }
    __syncthreads();

    {
        const uint4* g = (const uint4*)(xb + (size_t)node0 * 128);
#pragma unroll
        for (int i = 0; i < 4; ++i) {
            int chunk = t + 256 * i;
            *(uint4*)&As[(chunk >> 4) * 136 + (chunk & 15) * 8] = g[chunk];
        }
    }
    __syncthreads();
#pragma unroll
    for (int kt = 0; kt < 4; ++kt) {
        bf16x8 a = *(const bf16x8*)&As[lrow * 136 + kt * 32 + lkq];
        const bf16x8* bp = (const bf16x8*)w1rp + (kt * 8) * 64 + l;
#pragma unroll
        for (int nt = 0; nt < 8; ++nt)
            acc[nt] = __builtin_amdgcn_mfma_f32_16x16x32_bf16(a, bp[nt * 64], acc[nt], 0, 0, 0);
    }
    __syncthreads();

    // h (relu + bias) back into As as bf16.
#pragma unroll
    for (int nt = 0; nt < 8; ++nt) {
        int n = nt * 16 + cq;
        float bias = b1[n];
#pragma unroll
        for (int r = 0; r < 4; ++r) {
            float hv = fmaxf(acc[nt][r] + bias, 0.0f);
            As[(w * 16 + rq + r) * 136 + n] = f2bf(hv);
        }
    }
    __syncthreads();

    // Both second-layer products from the same h fragments.
    f32x4 acc2[4];  // h@W2l -> pb
    f32x4 acc3[4];  // h@W2r -> partial out
#pragma unroll
    for (int i = 0; i < 4; ++i) {
        acc2[i] = (f32x4){0.f, 0.f, 0.f, 0.f};
        acc3[i] = (f32x4){0.f, 0.f, 0.f, 0.f};
    }
#pragma unroll
    for (int kt = 0; kt < 4; ++kt) {
        bf16x8 a = *(const bf16x8*)&As[lrow * 136 + kt * 32 + lkq];
        const bf16x8* bpl = (const bf16x8*)w2lp + (kt * 4) * 64 + l;
        const bf16x8* bpr = (const bf16x8*)w2rp + (kt * 4) * 64 + l;
#pragma unroll
        for (int nt = 0; nt < 4; ++nt) {
            acc2[nt] = __builtin_amdgcn_mfma_f32_16x16x32_bf16(a, bpl[nt * 64], acc2[nt], 0, 0, 0);
            acc3[nt] = __builtin_amdgcn_mfma_f32_16x16x32_bf16(a, bpr[nt * 64], acc3[nt], 0, 0, 0);
        }
    }

    // Partial out = h@W2r + b2, straight from accumulators.
#pragma unroll
    for (int nt = 0; nt < 4; ++nt) {
        int n = nt * 16 + cq;
        float bias = b2[n];
#pragma unroll
        for (int r = 0; r < 4; ++r) {
            int row = node0 + w * 16 + rq + r;
            if (row < NN)
                out[(size_t)row * 64 + n] = acc3[nt][r] + bias;
        }
    }

    // pb = bf16(h@W2l) via LDS repack for vectorized store.
    __syncthreads();
#pragma unroll
    for (int nt = 0; nt < 4; ++nt)
#pragma unroll
        for (int r = 0; r < 4; ++r)
            As[(w * 16 + rq + r) * 136 + nt * 16 + cq] = f2bf(acc2[nt][r]);
    __syncthreads();
    {
        uint4* g = (uint4*)(pb + (size_t)node0 * 64);
#pragma unroll
        for (int i = 0; i < 2; ++i) {
            int chunk = t + 256 * i;
            if (node0 + (chunk >> 3) < NN)
                g[chunk] = *(const uint4*)&As[(chunk >> 3) * 136 + (chunk & 7) * 8];
        }
    }
}

extern "C" void kernel_launch(void* const* d_in, const int* in_sizes, int n_in,
                              void* d_out, int out_size, void* d_ws, size_t ws_size,
                              hipStream_t stream) {
    const float* x   = (const float*)d_in[0];
    const int*   ei  = (const int*)d_in[1];
    const float* W1l = (const float*)d_in[2];
    const float* W1r = (const float*)d_in[3];
    const float* b1  = (const float*)d_in[4];
    const float* W2l = (const float*)d_in[5];
    const float* W2r = (const float*)d_in[6];
    const float* b2  = (const float*)d_in[7];

    const int* src = ei;
    const int* dst = ei + NE;

    int*      ws_i   = (int*)d_ws;
    int*      cc     = ws_i + OFF_CC;
    int*      rstart = ws_i + OFF_RST;
    int*      rdeg   = ws_i + OFF_RDG;
    unsigned* stage  = (unsigned*)(ws_i + OFF_STAGE);
    ushort*   xb     = (ushort*)(ws_i + OFF_XB);
    unsigned* xf8    = (unsigned*)(ws_i + OFF_XF8);
    ushort*   pb     = (ushort*)(ws_i + OFF_XF8);   // aliases xf8 (disjoint lifetime)
    ushort*   meanb  = (ushort*)(ws_i + OFF_MEANB);
    ushort*   w1lp   = (ushort*)(ws_i + OFF_W1LP);
    ushort*   w1rp   = (ushort*)(ws_i + OFF_W1RP);
    ushort*   w2lp   = (ushort*)(ws_i + OFF_W2LP);
    ushort*   w2rp   = (ushort*)(ws_i + OFF_W2RP);

    hipMemsetAsync(cc, 0, 1024 * sizeof(int), stream);

    // Fused prep v2: cpart (1024-thread) + pack + cvt in one concurrent launch.
    prep_kernel<<<PREP_GRID, 1024, 0, stream>>>(
        x, xb, xf8, W1l, W1r, W2l, W2r, w1lp, w1rp, w2lp, w2rp, src, dst, cc, stage);
    sort_kernel<<<KB, 256, 0, stream>>>(stage, cc, rstart, rdeg);

    // Layer 1 + both second-layer products (gemm2 folded in).
    agg1g_kernel<<<NN / 32, 256, 0, stream>>>(stage, rstart, rdeg, xf8, meanb);
    gemm1_kernel<<<(NN + 63) / 64, 256, 0, stream>>>(meanb, xb, w1lp, w1rp, b1,
                                                     w2lp, w2rp, b2, pb, (float*)d_out);

    // Layer 2: gather pb, mean, add into partial out.
    agg2g_kernel<<<NN / 16, 256, 0, stream>>>(stage, rstart, rdeg, pb, (float*)d_out);
}